// Round 2
// baseline (503.211 us; speedup 1.0000x reference)
//
#include <hip/hip_runtime.h>
#include <math.h>

// Fused pool+combine, single pass, zero workspace traffic.
//
//   in1: (8,256, 64, 64)  k=2   in2: (8,128,128,128) k=4
//   in3: (8, 64,256,256)  k=8   in4: (8, 32,512,512) k=16
//   out[b,c,h,w] = relu(ff + p1[c%256] + p2[c%128] + p3[c%64] + p4[c%32])
//
// Block = (b, m=c%32, row-quadrant s). Pool the reuse set for this block's
// 8-row band into 15 KB LDS, barrier, sum+relu+store. Each input byte is
// read exactly once globally.
//
// Round-2 change: in4 (k=16) and in3 (k=8) pooling now use LANE-CONTIGUOUS
// float4 loads (64 lanes x 16 B = 1 KB/instruction, full line utilization)
// with __shfl_xor horizontal window reduction, instead of the previous
// 64 B- / 32 B-strided 16 B accesses (25% / 50% per-instruction line use).
// That covers 75% of all HBM traffic. in2/in1/ff/out were already contiguous.

__device__ __forceinline__ float max4(float4 v) {
    return fmaxf(fmaxf(v.x, v.y), fmaxf(v.z, v.w));
}

__global__ __launch_bounds__(256, 4) void fused_kernel(
    const float* __restrict__ in1, const float* __restrict__ in2,
    const float* __restrict__ in3, const float* __restrict__ in4,
    const float* __restrict__ ff, float* __restrict__ out) {

    __shared__ float p4s[8][32];        //  1 KB, channel m
    __shared__ float p3s[2][8][32];     //  2 KB, channels m+32j
    __shared__ float p2s[4][8][32];     //  4 KB
    __shared__ float p1s[8][8][32];     //  8 KB

    const int tid = threadIdx.x;
    const int bid = blockIdx.x;
    const int s   = bid & 3;            // row quadrant: oh in [8s, 8s+8)
    const int m   = (bid >> 2) & 31;    // channel mod 32
    const int b   = bid >> 7;           // batch

    const int wv   = tid >> 6;          // wave 0..3
    const int lane = tid & 63;

    // ---- in4 (k=16, W=512), channel m. Wave wv owns pooled rows 2wv..2wv+1.
    // Lane l loads float4 at source col 4l (first half-row, pooled cols 0..15)
    // and 256+4l (second half, pooled cols 16..31): both fully contiguous.
    {
        const float* base_c = in4 + (size_t)(b * 32 + m) * (512 * 512);
#pragma unroll
        for (int i = 0; i < 2; ++i) {
            const int pr = wv * 2 + i;              // band row 0..7
            const int oh = s * 8 + pr;              // pooled row
            const float* rp = base_c + (size_t)(oh * 16) * 512 + 4 * lane;
            float m0 = -INFINITY, m1 = -INFINITY;
#pragma unroll
            for (int r = 0; r < 16; ++r) {
                m0 = fmaxf(m0, max4(*(const float4*)(rp + r * 512)));
                m1 = fmaxf(m1, max4(*(const float4*)(rp + r * 512 + 256)));
            }
            // window = 16 source cols = 4 lanes
            m0 = fmaxf(m0, __shfl_xor(m0, 1));
            m0 = fmaxf(m0, __shfl_xor(m0, 2));
            m1 = fmaxf(m1, __shfl_xor(m1, 1));
            m1 = fmaxf(m1, __shfl_xor(m1, 2));
            if ((lane & 3) == 0) {
                const int c = lane >> 2;            // 0..15
                p4s[pr][c]      = m0;
                p4s[pr][16 + c] = m1;
            }
        }
    }

    // ---- in3 (k=8, W=256), channels m, m+32. Wave wv -> channel j=wv>>1,
    // pooled rows (wv&1)*4..+4. Lane l loads float4 at col 4l: one wave
    // instruction covers an entire 256-float source row, contiguous.
    {
        const int j = wv >> 1;
        const float* base_c = in3 + (size_t)(b * 64 + m + 32 * j) * (256 * 256);
#pragma unroll
        for (int i = 0; i < 4; ++i) {
            const int pr = (wv & 1) * 4 + i;        // band row 0..7
            const int oh = s * 8 + pr;
            const float* rp = base_c + (size_t)(oh * 8) * 256 + 4 * lane;
            float mm = -INFINITY;
#pragma unroll
            for (int r = 0; r < 8; ++r)
                mm = fmaxf(mm, max4(*(const float4*)(rp + r * 256)));
            // window = 8 source cols = 2 lanes
            mm = fmaxf(mm, __shfl_xor(mm, 1));
            if ((lane & 1) == 0)
                p3s[j][pr][lane >> 1] = mm;
        }
    }

    // ---- in2 (k=4, W=128): lane stride 16 B = access size, already
    // contiguous (lanes 0..31 cover one full 128-float source row).
    const int col = tid & 31;           // pooled col 0..31
    const int row = tid >> 5;           // 0..7 within band
    const int oh  = s * 8 + row;        // pooled row
#pragma unroll
    for (int j = 0; j < 4; ++j) {
        const float* p = in2 + ((size_t)(b * 128 + m + 32 * j) * 128 + oh * 4) * 128
                             + col * 4;
        float mx = -INFINITY;
#pragma unroll
        for (int r = 0; r < 4; ++r)
            mx = fmaxf(mx, max4(*(const float4*)(p + r * 128)));
        p2s[j][row][col] = mx;
    }

    // ---- in1 (k=2, W=64): float2 loads, lane stride 8 B = access size.
#pragma unroll
    for (int j = 0; j < 8; ++j) {
        const float* p = in1 + ((size_t)(b * 256 + m + 32 * j) * 64 + oh * 2) * 64
                             + col * 2;
        float2 v0 = *(const float2*)p;
        float2 v1 = *(const float2*)(p + 64);
        p1s[j][row][col] = fmaxf(fmaxf(v0.x, v0.y), fmaxf(v1.x, v1.y));
    }

    __syncthreads();

    // ---- combine + relu + store: 16 channels x 8 rows x 32 cols.
    // One wave per channel per pass; 64 lanes = 64 contiguous float4 = 1 KB.
    const int ci  = tid >> 6;           // wave id = channel-within-pass
    const int r2  = lane >> 3;          // row 0..7
    const int q   = lane & 7;           // float4 col 0..7
#pragma unroll
    for (int pass = 0; pass < 4; ++pass) {
        const int i = pass * 4 + ci;                    // 0..15
        const int c = m + 32 * i;                       // output channel
        const size_t o4 = (size_t)(b * 512 + c) * 256 + (s * 8 + r2) * 8 + q;
        float4 a  = ((const float4*)ff)[o4];
        float4 v1 = *(const float4*)&p1s[i & 7][r2][q * 4];
        float4 v2 = *(const float4*)&p2s[i & 3][r2][q * 4];
        float4 v3 = *(const float4*)&p3s[i & 1][r2][q * 4];
        float4 v4 = *(const float4*)&p4s[r2][q * 4];
        float4 o;
        o.x = fmaxf(a.x + v1.x + v2.x + v3.x + v4.x, 0.0f);
        o.y = fmaxf(a.y + v1.y + v2.y + v3.y + v4.y, 0.0f);
        o.z = fmaxf(a.z + v1.z + v2.z + v3.z + v4.z, 0.0f);
        o.w = fmaxf(a.w + v1.w + v2.w + v3.w + v4.w, 0.0f);
        ((float4*)out)[o4] = o;
    }
}

extern "C" void kernel_launch(void* const* d_in, const int* in_sizes, int n_in,
                              void* d_out, int out_size, void* d_ws, size_t ws_size,
                              hipStream_t stream) {
    const float* in1 = (const float*)d_in[0];
    const float* in2 = (const float*)d_in[1];
    const float* in3 = (const float*)d_in[2];
    const float* in4 = (const float*)d_in[3];
    const float* ff  = (const float*)d_in[4];
    float* out = (float*)d_out;
    (void)d_ws; (void)ws_size;

    fused_kernel<<<1024, 256, 0, stream>>>(in1, in2, in3, in4, ff, out);
}